// Round 1
// baseline (278.163 us; speedup 1.0000x reference)
//
#include <hip/hip_runtime.h>
#include <hip/hip_bf16.h>

// Collision distance evaluator:
//   per row b: qi = conj(q)/|q|^2 ; p' = qi * (p,0) * conj(qi) ; p'' = p' - trans
//   mask = p'' in [lo,hi] box ; dist = (cnt>0 ? -sum(||p''|| over mask)/cnt : 1) * 1e4

#define DIST_COEFF 10000.0f

__global__ __launch_bounds__(256) void collision_dist_kernel(
    const float* __restrict__ trans,
    const float* __restrict__ quat,
    const float* __restrict__ pc,
    float* __restrict__ out,
    int N)
{
    const int b = blockIdx.x;

    // --- per-row uniform setup (each thread redundantly; cheap) ---
    const float qx = quat[b * 4 + 0];
    const float qy = quat[b * 4 + 1];
    const float qz = quat[b * 4 + 2];
    const float qw = quat[b * 4 + 3];
    const float n2 = qx * qx + qy * qy + qz * qz + qw * qw;
    const float inv = 1.0f / n2;
    // qi = conj(q)/n2 = (ax,ay,az,aw)
    const float ax = -qx * inv;
    const float ay = -qy * inv;
    const float az = -qz * inv;
    const float aw =  qw * inv;

    const float tx = trans[b * 3 + 0];
    const float ty = trans[b * 3 + 1];
    const float tz = trans[b * 3 + 2];

    // box constants (f32, matching numpy f32 arithmetic)
    const float cx = -0.001782f, cy = 1.005e-05f, cz = 0.0431621f;
    const float hx = 0.204416f * 0.5f + 0.001f;
    const float hy = 0.0632517f * 0.5f + 0.001f;
    const float hz = 0.1381738f * 0.5f + 0.001f;
    const float lox = cx - hx, hix = cx + hx;
    const float loy = cy - hy, hiy = cy + hy;
    const float loz = cz - hz, hiz = cz + hz;

    const float* row = pc + (size_t)b * (size_t)N * 3u;

    float s = 0.0f;
    int cnt = 0;

    // process one point (px,py,pz)
    auto point = [&](float px, float py, float pz) {
        // t = qmul(qi, (p,0)):  w1 = -dot(a,p), v1 = aw*p + cross(a,p)
        const float w1  = -(ax * px + ay * py + az * pz);
        const float v1x = aw * px + (ay * pz - az * py);
        const float v1y = aw * py + (az * px - ax * pz);
        const float v1z = aw * pz + (ax * py - ay * px);
        // r = qmul(t, conj(qi)) vector part: -w1*a + aw*v1 - cross(v1,a)
        const float rx = -w1 * ax + aw * v1x - (v1y * az - v1z * ay);
        const float ry = -w1 * ay + aw * v1y - (v1z * ax - v1x * az);
        const float rz = -w1 * az + aw * v1z - (v1x * ay - v1y * ax);
        const float fx = rx - tx;
        const float fy = ry - ty;
        const float fz = rz - tz;
        const bool inside = (fx >= lox) & (fx <= hix) &
                            (fy >= loy) & (fy <= hiy) &
                            (fz >= loz) & (fz <= hiz);
        if (inside) {
            cnt += 1;
            s += sqrtf(fx * fx + fy * fy + fz * fz);
        }
    };

    // vectorized main loop: chunks of 4 points = 12 floats = 3x float4
    const int nchunk = N >> 2;                 // N assumed large; tail below
    const float4* row4 = reinterpret_cast<const float4*>(row);
    for (int c = threadIdx.x; c < nchunk; c += blockDim.x) {
        const float4 v0 = row4[c * 3 + 0];
        const float4 v1 = row4[c * 3 + 1];
        const float4 v2 = row4[c * 3 + 2];
        point(v0.x, v0.y, v0.z);
        point(v0.w, v1.x, v1.y);
        point(v1.z, v1.w, v2.x);
        point(v2.y, v2.z, v2.w);
    }
    // scalar tail (N % 4 points)
    for (int i = (nchunk << 2) + threadIdx.x; i < N; i += blockDim.x) {
        point(row[i * 3 + 0], row[i * 3 + 1], row[i * 3 + 2]);
    }

    // --- wave (64-lane) reduction ---
    float fc = (float)cnt;
    #pragma unroll
    for (int off = 32; off > 0; off >>= 1) {
        s  += __shfl_down(s, off, 64);
        fc += __shfl_down(fc, off, 64);
    }

    // --- cross-wave reduction via LDS ---
    __shared__ float ss[8];
    __shared__ float sc[8];
    const int lane = threadIdx.x & 63;
    const int wid  = threadIdx.x >> 6;
    if (lane == 0) { ss[wid] = s; sc[wid] = fc; }
    __syncthreads();
    if (threadIdx.x == 0) {
        float S = 0.0f, C = 0.0f;
        const int nw = (blockDim.x + 63) >> 6;
        for (int w = 0; w < nw; ++w) { S += ss[w]; C += sc[w]; }
        const float dist = (C > 0.0f) ? (-S / C) : 1.0f;
        out[b] = dist * DIST_COEFF;
    }
}

extern "C" void kernel_launch(void* const* d_in, const int* in_sizes, int n_in,
                              void* d_out, int out_size, void* d_ws, size_t ws_size,
                              hipStream_t stream) {
    const float* trans = (const float*)d_in[0];
    const float* quat  = (const float*)d_in[1];
    const float* pc    = (const float*)d_in[2];
    float* out = (float*)d_out;

    const int B = in_sizes[0] / 3;                    // 4096
    const int N = (int)((long long)in_sizes[2] / (3LL * B)); // 4096

    collision_dist_kernel<<<B, 256, 0, stream>>>(trans, quat, pc, out, N);
}

// Round 3
// 277.320 us; speedup vs baseline: 1.0030x; 1.0030x over previous
//
#include <hip/hip_runtime.h>
#include <hip/hip_bf16.h>

#define DIST_COEFF 10000.0f

// address-space casts for global_load_lds
#define AS1(p) ((__attribute__((address_space(1))) void*)(p))
#define AS3(p) ((__attribute__((address_space(3))) void*)(p))

// ---------------------------------------------------------------------------
// Staged kernel: 1 block (256 thr = 4 waves) per batch row.
// Loop over 1024-point chunks (12 KB LDS):
//   stage: 3x block-wide global_load_lds dwordx4 (lane-contiguous, minimal
//          cache-line traffic)  -> __syncthreads (drains vmcnt before barrier)
//   read:  each thread 4 points at float-stride 3 (bank-benign) -> accumulate
//   -> __syncthreads (protect LDS overwrite next iteration)
// Requires N % 1024 == 0 (N=4096 here); generic fallback otherwise.
// ---------------------------------------------------------------------------
__global__ __launch_bounds__(256) void collision_dist_staged(
    const float* __restrict__ trans,
    const float* __restrict__ quat,
    const float* __restrict__ pc,
    float* __restrict__ out,
    int N)
{
    const int b    = blockIdx.x;
    const int tid  = threadIdx.x;
    const int w    = tid >> 6;
    const int lane = tid & 63;

    // --- per-row constants ---
    const float qx = quat[b * 4 + 0];
    const float qy = quat[b * 4 + 1];
    const float qz = quat[b * 4 + 2];
    const float qw = quat[b * 4 + 3];
    const float inv = 1.0f / (qx * qx + qy * qy + qz * qz + qw * qw);
    // qi = conj(q)/|q|^2 = (a, aw)
    const float ax = -qx * inv, ay = -qy * inv, az = -qz * inv, aw = qw * inv;
    // rotation by qi as 3x3 matrix: (aw^2-|a|^2) p + 2(a.p)a + 2 aw (a x p)
    const float d = aw * aw - (ax * ax + ay * ay + az * az);
    const float m00 = d + 2.0f * ax * ax;
    const float m01 = 2.0f * ax * ay - 2.0f * aw * az;
    const float m02 = 2.0f * ax * az + 2.0f * aw * ay;
    const float m10 = 2.0f * ay * ax + 2.0f * aw * az;
    const float m11 = d + 2.0f * ay * ay;
    const float m12 = 2.0f * ay * az - 2.0f * aw * ax;
    const float m20 = 2.0f * az * ax - 2.0f * aw * ay;
    const float m21 = 2.0f * az * ay + 2.0f * aw * ax;
    const float m22 = d + 2.0f * az * az;

    const float tx = trans[b * 3 + 0];
    const float ty = trans[b * 3 + 1];
    const float tz = trans[b * 3 + 2];

    const float cx = -0.001782f, cy = 1.005e-05f, cz = 0.0431621f;
    const float hx = 0.204416f * 0.5f + 0.001f;
    const float hy = 0.0632517f * 0.5f + 0.001f;
    const float hz = 0.1381738f * 0.5f + 0.001f;
    const float lox = cx - hx, hix = cx + hx;
    const float loy = cy - hy, hiy = cy + hy;
    const float loz = cz - hz, hiz = cz + hz;

    // 1024 points x 3 floats = 3072 floats = 12288 B
    __shared__ float lds[3072];

    const float* rowp  = pc + (size_t)b * (size_t)N * 3u;
    const float4* row4 = reinterpret_cast<const float4*>(rowp);

    const int nchunk = N >> 10;      // 1024-point chunks
    float s = 0.0f, c = 0.0f;

    for (int ck = 0; ck < nchunk; ++ck) {
        // stage 1024 points = 768 float4, block-wide, lane-contiguous.
        // wave w writes lds float4 slots [j*256 + w*64 .. +64) from matching
        // global float4s; LDS base is wave-uniform, HW adds lane*16.
        const float4* g4 = row4 + (size_t)ck * 768u;
        #pragma unroll
        for (int j = 0; j < 3; ++j) {
            __builtin_amdgcn_global_load_lds(
                AS1(g4 + j * 256 + tid),                    // per-lane global src
                AS3(lds + (j * 256 + w * 64) * 4),          // wave-uniform LDS base
                16, 0, 0);
        }
        __syncthreads();   // drains vmcnt(0) before barrier -> LDS valid

        #pragma unroll
        for (int r = 0; r < 4; ++r) {
            const int p = r * 256 + tid;       // point index in chunk
            const float px = lds[3 * p + 0];
            const float py = lds[3 * p + 1];
            const float pz = lds[3 * p + 2];
            const float fx = fmaf(m00, px, fmaf(m01, py, fmaf(m02, pz, -tx)));
            const float fy = fmaf(m10, px, fmaf(m11, py, fmaf(m12, pz, -ty)));
            const float fz = fmaf(m20, px, fmaf(m21, py, fmaf(m22, pz, -tz)));
            const bool inside = (fx >= lox) & (fx <= hix) &
                                (fy >= loy) & (fy <= hiy) &
                                (fz >= loz) & (fz <= hiz);
            const float nrm = sqrtf(fmaf(fx, fx, fmaf(fy, fy, fz * fz)));
            s += inside ? nrm : 0.0f;
            c += inside ? 1.0f : 0.0f;
        }
        __syncthreads();   // all reads retired before next chunk overwrites
    }

    // wave reduction
    #pragma unroll
    for (int off = 32; off > 0; off >>= 1) {
        s += __shfl_down(s, off, 64);
        c += __shfl_down(c, off, 64);
    }

    __shared__ float rs[4], rc[4];
    if (lane == 0) { rs[w] = s; rc[w] = c; }
    __syncthreads();
    if (tid == 0) {
        const float S = rs[0] + rs[1] + rs[2] + rs[3];
        const float C = rc[0] + rc[1] + rc[2] + rc[3];
        const float dist = (C > 0.0f) ? (-S / C) : 1.0f;
        out[b] = dist * DIST_COEFF;
    }
}

// ---------------------------------------------------------------------------
// Generic fallback (any N): round-1 kernel.
// ---------------------------------------------------------------------------
__global__ __launch_bounds__(256) void collision_dist_generic(
    const float* __restrict__ trans,
    const float* __restrict__ quat,
    const float* __restrict__ pc,
    float* __restrict__ out,
    int N)
{
    const int b = blockIdx.x;
    const float qx = quat[b * 4 + 0], qy = quat[b * 4 + 1];
    const float qz = quat[b * 4 + 2], qw = quat[b * 4 + 3];
    const float inv = 1.0f / (qx * qx + qy * qy + qz * qz + qw * qw);
    const float ax = -qx * inv, ay = -qy * inv, az = -qz * inv, aw = qw * inv;
    const float tx = trans[b * 3 + 0], ty = trans[b * 3 + 1], tz = trans[b * 3 + 2];

    const float cx = -0.001782f, cy = 1.005e-05f, cz = 0.0431621f;
    const float hx = 0.204416f * 0.5f + 0.001f;
    const float hy = 0.0632517f * 0.5f + 0.001f;
    const float hz = 0.1381738f * 0.5f + 0.001f;
    const float lox = cx - hx, hix = cx + hx;
    const float loy = cy - hy, hiy = cy + hy;
    const float loz = cz - hz, hiz = cz + hz;

    const float* row = pc + (size_t)b * (size_t)N * 3u;
    float s = 0.0f, c = 0.0f;

    for (int i = threadIdx.x; i < N; i += blockDim.x) {
        const float px = row[i * 3 + 0];
        const float py = row[i * 3 + 1];
        const float pz = row[i * 3 + 2];
        const float w1  = -(ax * px + ay * py + az * pz);
        const float v1x = aw * px + (ay * pz - az * py);
        const float v1y = aw * py + (az * px - ax * pz);
        const float v1z = aw * pz + (ax * py - ay * px);
        const float fx = -w1 * ax + aw * v1x - (v1y * az - v1z * ay) - tx;
        const float fy = -w1 * ay + aw * v1y - (v1z * ax - v1x * az) - ty;
        const float fz = -w1 * az + aw * v1z - (v1x * ay - v1y * ax) - tz;
        const bool inside = (fx >= lox) & (fx <= hix) &
                            (fy >= loy) & (fy <= hiy) &
                            (fz >= loz) & (fz <= hiz);
        const float nrm = sqrtf(fx * fx + fy * fy + fz * fz);
        s += inside ? nrm : 0.0f;
        c += inside ? 1.0f : 0.0f;
    }

    #pragma unroll
    for (int off = 32; off > 0; off >>= 1) {
        s += __shfl_down(s, off, 64);
        c += __shfl_down(c, off, 64);
    }
    __shared__ float rs[4], rc[4];
    const int lane = threadIdx.x & 63, w = threadIdx.x >> 6;
    if (lane == 0) { rs[w] = s; rc[w] = c; }
    __syncthreads();
    if (threadIdx.x == 0) {
        float S = 0.0f, C = 0.0f;
        for (int i = 0; i < 4; ++i) { S += rs[i]; C += rc[i]; }
        out[b] = ((C > 0.0f) ? (-S / C) : 1.0f) * DIST_COEFF;
    }
}

extern "C" void kernel_launch(void* const* d_in, const int* in_sizes, int n_in,
                              void* d_out, int out_size, void* d_ws, size_t ws_size,
                              hipStream_t stream) {
    const float* trans = (const float*)d_in[0];
    const float* quat  = (const float*)d_in[1];
    const float* pc    = (const float*)d_in[2];
    float* out = (float*)d_out;

    const int B = in_sizes[0] / 3;
    const int N = (int)((long long)in_sizes[2] / (3LL * B));

    if ((N & 1023) == 0) {
        collision_dist_staged<<<B, 256, 0, stream>>>(trans, quat, pc, out, N);
    } else {
        collision_dist_generic<<<B, 256, 0, stream>>>(trans, quat, pc, out, N);
    }
}

// Round 4
// 274.684 us; speedup vs baseline: 1.0127x; 1.0096x over previous
//
#include <hip/hip_runtime.h>
#include <hip/hip_bf16.h>

#define DIST_COEFF 10000.0f

// address-space casts for global_load_lds
#define AS1(p) ((__attribute__((address_space(1))) void*)(p))
#define AS3(p) ((__attribute__((address_space(3))) void*)(p))

// ---------------------------------------------------------------------------
// One-shot staged kernel: 1 block (256 thr = 4 waves) per batch row.
// Stage the WHOLE row (N=4096 points = 48 KB) into LDS with 12 wave-wide
// global_load_lds dwordx4 per wave (48 KB in flight per block -> max MLP),
// ONE __syncthreads, then each thread computes 16 points from LDS
// (float-stride-3 reads: 2 lanes/bank = conflict-free), wave+LDS reduce.
// 48 KB LDS -> 3 blocks/CU -> 12 waves/CU of TLP.
// Requires N % 1024 == 0 and N <= 4096; generic fallback otherwise.
// ---------------------------------------------------------------------------
__global__ __launch_bounds__(256) void collision_dist_oneshot(
    const float* __restrict__ trans,
    const float* __restrict__ quat,
    const float* __restrict__ pc,
    float* __restrict__ out,
    int N)
{
    const int b    = blockIdx.x;
    const int tid  = threadIdx.x;
    const int w    = tid >> 6;
    const int lane = tid & 63;

    // --- per-row constants ---
    const float qx = quat[b * 4 + 0];
    const float qy = quat[b * 4 + 1];
    const float qz = quat[b * 4 + 2];
    const float qw = quat[b * 4 + 3];
    const float inv = 1.0f / (qx * qx + qy * qy + qz * qz + qw * qw);
    // qi = conj(q)/|q|^2 = (a, aw)
    const float ax = -qx * inv, ay = -qy * inv, az = -qz * inv, aw = qw * inv;
    // rotation by qi as 3x3 matrix: (aw^2-|a|^2) p + 2(a.p)a + 2 aw (a x p)
    const float d = aw * aw - (ax * ax + ay * ay + az * az);
    const float m00 = d + 2.0f * ax * ax;
    const float m01 = 2.0f * ax * ay - 2.0f * aw * az;
    const float m02 = 2.0f * ax * az + 2.0f * aw * ay;
    const float m10 = 2.0f * ay * ax + 2.0f * aw * az;
    const float m11 = d + 2.0f * ay * ay;
    const float m12 = 2.0f * ay * az - 2.0f * aw * ax;
    const float m20 = 2.0f * az * ax - 2.0f * aw * ay;
    const float m21 = 2.0f * az * ay + 2.0f * aw * ax;
    const float m22 = d + 2.0f * az * az;

    const float tx = trans[b * 3 + 0];
    const float ty = trans[b * 3 + 1];
    const float tz = trans[b * 3 + 2];

    const float cx = -0.001782f, cy = 1.005e-05f, cz = 0.0431621f;
    const float hx = 0.204416f * 0.5f + 0.001f;
    const float hy = 0.0632517f * 0.5f + 0.001f;
    const float hz = 0.1381738f * 0.5f + 0.001f;
    const float lox = cx - hx, hix = cx + hx;
    const float loy = cy - hy, hiy = cy + hy;
    const float loz = cz - hz, hiz = cz + hz;

    // whole row: up to 4096 points x 3 floats = 12288 floats = 49152 B
    __shared__ float lds[12288];

    const float*  rowp = pc + (size_t)b * (size_t)N * 3u;
    const float4* row4 = reinterpret_cast<const float4*>(rowp);

    const int nf4 = (N * 3) >> 2;          // float4 count (N%1024==0 -> exact)
    // stage: block-wide, 256 float4 per step; wave w's uniform LDS base is
    // float4 slot (j*256 + w*64); HW adds lane*16 bytes.
    for (int j = 0; j < (nf4 >> 8); ++j) {
        __builtin_amdgcn_global_load_lds(
            AS1(row4 + j * 256 + tid),                 // per-lane global src
            AS3(lds + (size_t)(j * 256 + w * 64) * 4), // wave-uniform LDS base
            16, 0, 0);
    }
    __syncthreads();   // drains vmcnt(0) before barrier -> LDS valid

    float s = 0.0f, c = 0.0f;
    for (int r = 0; r < (N >> 8); ++r) {
        const int p = r * 256 + tid;
        const float px = lds[3 * p + 0];
        const float py = lds[3 * p + 1];
        const float pz = lds[3 * p + 2];
        const float fx = fmaf(m00, px, fmaf(m01, py, fmaf(m02, pz, -tx)));
        const float fy = fmaf(m10, px, fmaf(m11, py, fmaf(m12, pz, -ty)));
        const float fz = fmaf(m20, px, fmaf(m21, py, fmaf(m22, pz, -tz)));
        const bool inside = (fx >= lox) & (fx <= hix) &
                            (fy >= loy) & (fy <= hiy) &
                            (fz >= loz) & (fz <= hiz);
        const float nrm = sqrtf(fmaf(fx, fx, fmaf(fy, fy, fz * fz)));
        s += inside ? nrm : 0.0f;
        c += inside ? 1.0f : 0.0f;
    }

    // wave reduction
    #pragma unroll
    for (int off = 32; off > 0; off >>= 1) {
        s += __shfl_down(s, off, 64);
        c += __shfl_down(c, off, 64);
    }

    __shared__ float rs[4], rc[4];
    if (lane == 0) { rs[w] = s; rc[w] = c; }
    __syncthreads();
    if (tid == 0) {
        const float S = rs[0] + rs[1] + rs[2] + rs[3];
        const float C = rc[0] + rc[1] + rc[2] + rc[3];
        const float dist = (C > 0.0f) ? (-S / C) : 1.0f;
        out[b] = dist * DIST_COEFF;
    }
}

// ---------------------------------------------------------------------------
// Generic fallback (any N).
// ---------------------------------------------------------------------------
__global__ __launch_bounds__(256) void collision_dist_generic(
    const float* __restrict__ trans,
    const float* __restrict__ quat,
    const float* __restrict__ pc,
    float* __restrict__ out,
    int N)
{
    const int b = blockIdx.x;
    const float qx = quat[b * 4 + 0], qy = quat[b * 4 + 1];
    const float qz = quat[b * 4 + 2], qw = quat[b * 4 + 3];
    const float inv = 1.0f / (qx * qx + qy * qy + qz * qz + qw * qw);
    const float ax = -qx * inv, ay = -qy * inv, az = -qz * inv, aw = qw * inv;
    const float tx = trans[b * 3 + 0], ty = trans[b * 3 + 1], tz = trans[b * 3 + 2];

    const float cx = -0.001782f, cy = 1.005e-05f, cz = 0.0431621f;
    const float hx = 0.204416f * 0.5f + 0.001f;
    const float hy = 0.0632517f * 0.5f + 0.001f;
    const float hz = 0.1381738f * 0.5f + 0.001f;
    const float lox = cx - hx, hix = cx + hx;
    const float loy = cy - hy, hiy = cy + hy;
    const float loz = cz - hz, hiz = cz + hz;

    const float* row = pc + (size_t)b * (size_t)N * 3u;
    float s = 0.0f, c = 0.0f;

    for (int i = threadIdx.x; i < N; i += blockDim.x) {
        const float px = row[i * 3 + 0];
        const float py = row[i * 3 + 1];
        const float pz = row[i * 3 + 2];
        const float w1  = -(ax * px + ay * py + az * pz);
        const float v1x = aw * px + (ay * pz - az * py);
        const float v1y = aw * py + (az * px - ax * pz);
        const float v1z = aw * pz + (ax * py - ay * px);
        const float fx = -w1 * ax + aw * v1x - (v1y * az - v1z * ay) - tx;
        const float fy = -w1 * ay + aw * v1y - (v1z * ax - v1x * az) - ty;
        const float fz = -w1 * az + aw * v1z - (v1x * ay - v1y * ax) - tz;
        const bool inside = (fx >= lox) & (fx <= hix) &
                            (fy >= loy) & (fy <= hiy) &
                            (fz >= loz) & (fz <= hiz);
        const float nrm = sqrtf(fx * fx + fy * fy + fz * fz);
        s += inside ? nrm : 0.0f;
        c += inside ? 1.0f : 0.0f;
    }

    #pragma unroll
    for (int off = 32; off > 0; off >>= 1) {
        s += __shfl_down(s, off, 64);
        c += __shfl_down(c, off, 64);
    }
    __shared__ float rs[4], rc[4];
    const int lane = threadIdx.x & 63, w = threadIdx.x >> 6;
    if (lane == 0) { rs[w] = s; rc[w] = c; }
    __syncthreads();
    if (threadIdx.x == 0) {
        float S = 0.0f, C = 0.0f;
        for (int i = 0; i < 4; ++i) { S += rs[i]; C += rc[i]; }
        out[b] = ((C > 0.0f) ? (-S / C) : 1.0f) * DIST_COEFF;
    }
}

extern "C" void kernel_launch(void* const* d_in, const int* in_sizes, int n_in,
                              void* d_out, int out_size, void* d_ws, size_t ws_size,
                              hipStream_t stream) {
    const float* trans = (const float*)d_in[0];
    const float* quat  = (const float*)d_in[1];
    const float* pc    = (const float*)d_in[2];
    float* out = (float*)d_out;

    const int B = in_sizes[0] / 3;
    const int N = (int)((long long)in_sizes[2] / (3LL * B));

    if ((N & 1023) == 0 && N <= 4096) {
        collision_dist_oneshot<<<B, 256, 0, stream>>>(trans, quat, pc, out, N);
    } else {
        collision_dist_generic<<<B, 256, 0, stream>>>(trans, quat, pc, out, N);
    }
}